// Round 7
// baseline (111.322 us; speedup 1.0000x reference)
//
#include <hip/hip_runtime.h>
#include <math.h>

#define NK        10000
#define LSEQ      512
#define KSMAX     11
#define NKEY      3072              // key = (((dl-1)*3 + ksi) << 1) | padded ; dl<=512 safe
#define SCAN_N    4096
#define TOT_SLOT  19456             // 1216 blocks * 16 ; >= 10000 + 3*NKEY worst case
#define GRID_MAIN 1216
#define ROWS_DW   (514 * 4)         // staged f16x8 rows (pos=-1..512), dwords
#define RED_OFF   ROWS_DW
#define SM_DW     (ROWS_DW + 256 * 10)   // 18464 B

typedef _Float16 half2v __attribute__((ext_vector_type(2)));
union H2U { half2v h; unsigned int u; };

__device__ __forceinline__ int ks_index(float w7, float w8, float w9, float w10) {
    if (w7 == 0.f && w8 == 0.f && w9 == 0.f && w10 == 0.f) return 0;
    if (w9 == 0.f && w10 == 0.f) return 1;
    return 2;
}

// ---------------- pass 1: bucket kernels by (dl, ks, padded) into quad-padded groups ----
__global__ __launch_bounds__(1024) void bucket_kernel(
    const float* __restrict__ W, const int* __restrict__ dil, const int* __restrict__ lo,
    int* __restrict__ ord) {
    __shared__ unsigned cnt[NKEY];
    __shared__ unsigned cur[NKEY];
    __shared__ unsigned sa[SCAN_N];
    __shared__ unsigned sb[SCAN_N];
    const int tid = threadIdx.x;
    for (int i = tid; i < NKEY; i += 1024) cnt[i] = 0;
    __syncthreads();
    for (int i = tid; i < NK; i += 1024) {
        const float* wr = W + (size_t)i * KSMAX;
        int ksi = ks_index(wr[7], wr[8], wr[9], wr[10]);
        int ks = 7 + 2 * ksi;
        int d = dil[i];
        int pd = (lo[i] - LSEQ + d * (ks - 1)) > 0;
        int key = (((d - 1) * 3 + ksi) << 1) | pd;
        atomicAdd(&cnt[key], 1u);
    }
    __syncthreads();
    for (int i = tid; i < SCAN_N; i += 1024)
        sa[i] = (i < NKEY) ? ((cnt[i] + 3u) & ~3u) : 0u;   // quad-padded counts
    __syncthreads();
    unsigned* A = sa; unsigned* B = sb;
    for (int off = 1; off < SCAN_N; off <<= 1) {           // Hillis-Steele inclusive scan
        for (int i = tid; i < SCAN_N; i += 1024)
            B[i] = A[i] + ((i >= off) ? A[i - off] : 0u);
        unsigned* t = A; A = B; B = t;
        __syncthreads();
    }
    for (int i = tid; i < NKEY; i += 1024)
        cur[i] = A[i] - ((cnt[i] + 3u) & ~3u);             // exclusive group starts
    for (int i = tid; i < TOT_SLOT; i += 1024) ord[i] = -1;
    __syncthreads();
    for (int i = tid; i < NK; i += 1024) {
        const float* wr = W + (size_t)i * KSMAX;
        int ksi = ks_index(wr[7], wr[8], wr[9], wr[10]);
        int ks = 7 + 2 * ksi;
        int d = dil[i];
        int pd = (lo[i] - LSEQ + d * (ks - 1)) > 0;
        int key = (((d - 1) * 3 + ksi) << 1) | pd;
        unsigned slot = atomicAdd(&cur[key], 1u);
        ord[slot] = i;
    }
}

// ---------------- main kernel: one wave owns a quad of same-(dl,ks,pd) kernels ----------
template <int KS>
__device__ __forceinline__ void run_quad(const float4* __restrict__ rows,
                                         const half2v (&wh)[4][KSMAX], const half2v (&bb)[4],
                                         const int (&pq)[4], const int (&lkq)[4],
                                         int dl, int r_lo, int r_hi, int lane,
                                         half2v (&m)[4][4], half2v (&c)[4][4]) {
    const half2v one2  = {(_Float16)1.0f, (_Float16)1.0f};
    const half2v zero2 = {(_Float16)0.0f, (_Float16)0.0f};
    const half2v big2  = {(_Float16)16384.0f, (_Float16)16384.0f};
    const half2v ninf2 = {(_Float16)(-INFINITY), (_Float16)(-INFINITY)};
    for (int r0 = r_lo; r0 < r_hi; r0 += 64) {
        const int r = r0 + lane;
        half2v a[4][4];
        #pragma unroll
        for (int q = 0; q < 4; ++q) {
            #pragma unroll
            for (int i = 0; i < 4; ++i) a[q][i] = bb[q];
        }
        int pos = r;
        #pragma unroll
        for (int j = 0; j < KS; ++j) {
            int pc = min(max(pos, -1), LSEQ);          // v_med3_i32; rows -1/512 are zeros
            float4 rr = rows[pc + 1];                  // ONE ds_read_b128 serves 4 kernels
            half2v v0 = ((half2v*)&rr)[0];
            half2v v1 = ((half2v*)&rr)[1];
            half2v v2 = ((half2v*)&rr)[2];
            half2v v3 = ((half2v*)&rr)[3];
            #pragma unroll
            for (int q = 0; q < 4; ++q) {
                half2v wj = wh[q][j];
                a[q][0] += wj * v0;
                a[q][1] += wj * v1;
                a[q][2] += wj * v2;
                a[q][3] += wj * v3;
            }
            pos += dl;
        }
        #pragma unroll
        for (int q = 0; q < 4; ++q) {
            unsigned t = (unsigned)(r + pq[q]);        // t for this kernel
            bool valid = t < (unsigned)lkq[q];
            #pragma unroll
            for (int i = 0; i < 4; ++i) {
                half2v av = valid ? a[q][i] : ninf2;   // -inf: neutral for max, step()->0
                m[q][i] = __builtin_elementwise_max(m[q][i], av);
                c[q][i] += __builtin_elementwise_min(
                               __builtin_elementwise_max(av * big2, zero2), one2);
            }
        }
    }
}

__global__ __launch_bounds__(256) void rocket_kernel(
    const float* __restrict__ x, const float* __restrict__ W,
    const float* __restrict__ bias, const int* __restrict__ dil,
    const int* __restrict__ lo, const int* __restrict__ ord,
    float* __restrict__ out) {
    __shared__ __align__(16) float sm[SM_DW];
    const int tid = threadIdx.x;
    if (ord[blockIdx.x * 16] < 0) return;     // slots are dense: fully-dummy block exits early

    // ---- stage x -> LDS as f16, batch-major 16B rows; one row per thread ----
    #pragma unroll
    for (int i = 0; i < 2; ++i) {
        int p = tid + i * 256;
        half2v h0 = {(_Float16)x[0 * LSEQ + p], (_Float16)x[1 * LSEQ + p]};
        half2v h1 = {(_Float16)x[2 * LSEQ + p], (_Float16)x[3 * LSEQ + p]};
        half2v h2 = {(_Float16)x[4 * LSEQ + p], (_Float16)x[5 * LSEQ + p]};
        half2v h3 = {(_Float16)x[6 * LSEQ + p], (_Float16)x[7 * LSEQ + p]};
        float4 v;
        ((half2v*)&v)[0] = h0;
        ((half2v*)&v)[1] = h1;
        ((half2v*)&v)[2] = h2;
        ((half2v*)&v)[3] = h3;
        *(float4*)(sm + (size_t)(p + 1) * 4) = v;
    }
    if (tid < 4)           sm[tid] = 0.0f;                   // row pos=-1
    else if (tid < 8)      sm[513 * 4 + (tid - 4)] = 0.0f;   // row pos=512

    const int wave = tid >> 6;
    const int lane = tid & 63;

    // ---- quad setup (wave-uniform, scalarized via readfirstlane) ----
    int kq[4];
    #pragma unroll
    for (int q = 0; q < 4; ++q)
        kq[q] = __builtin_amdgcn_readfirstlane(ord[blockIdx.x * 16 + wave * 4 + q]);

    half2v wh[4][KSMAX];
    half2v bb[4];
    int pq[4], lkq[4];
    float w7 = 0.f, w8 = 0.f, w9 = 0.f, w10 = 0.f;
    int dl = 1;
    bool got = false;
    #pragma unroll
    for (int q = 0; q < 4; ++q) {
        int k = kq[q];
        if (k >= 0) {
            const float* wr = W + (size_t)k * KSMAX;
            #pragma unroll
            for (int j = 0; j < KSMAX; ++j) {
                _Float16 wf = (_Float16)wr[j];
                wh[q][j] = (half2v){wf, wf};
            }
            _Float16 bf = (_Float16)bias[k];
            bb[q] = (half2v){bf, bf};
            lkq[q] = lo[k];
            if (!got) { got = true; w7 = wr[7]; w8 = wr[8]; w9 = wr[9]; w10 = wr[10]; dl = dil[k]; }
        } else {
            #pragma unroll
            for (int j = 0; j < KSMAX; ++j) wh[q][j] = (half2v){(_Float16)0.f, (_Float16)0.f};
            bb[q] = (half2v){(_Float16)0.f, (_Float16)0.f};
            lkq[q] = 0;
        }
    }
    const int ksi = ks_index(w7, w8, w9, w10);   // group-uniform (key includes ks)
    const int ks = 7 + 2 * ksi;
    int r_lo = 0, r_hi = 0;
    #pragma unroll
    for (int q = 0; q < 4; ++q) {
        if (kq[q] >= 0) {
            pq[q] = (lkq[q] - LSEQ + dl * (ks - 1)) >> 1;   // lo = 512+2p-dl(ks-1)
            r_lo = min(r_lo, -pq[q]);
            r_hi = max(r_hi, lkq[q] - pq[q]);
        } else {
            pq[q] = 0;
        }
    }

    __syncthreads();   // rows visible to all waves

    const half2v ninf2 = {(_Float16)(-INFINITY), (_Float16)(-INFINITY)};
    const half2v zz    = {(_Float16)0.f, (_Float16)0.f};
    half2v m[4][4], c[4][4];
    #pragma unroll
    for (int q = 0; q < 4; ++q) {
        #pragma unroll
        for (int i = 0; i < 4; ++i) { m[q][i] = ninf2; c[q][i] = zz; }
    }

    const float4* rows = (const float4*)sm;
    if (ksi == 0)      run_quad<7 >(rows, wh, bb, pq, lkq, dl, r_lo, r_hi, lane, m, c);
    else if (ksi == 1) run_quad<9 >(rows, wh, bb, pq, lkq, dl, r_lo, r_hi, lane, m, c);
    else               run_quad<11>(rows, wh, bb, pq, lkq, dl, r_lo, r_hi, lane, m, c);

    // ---- wave-internal epilogue per quad entry (no barriers: same-wave DS ordering) ----
    unsigned int* red = (unsigned int*)(sm + RED_OFF);
    const int tb = tid * 10;                 // 40B stride, 8B aligned
    const int wbase = (tid & ~63) * 10;      // own wave's slice
    const int sub = lane & 7;
    const int dv = lane >> 3;                // 0..3 = max half2s, 4..7 = cnt half2s
    const bool ismax = dv < 4;
    #pragma unroll
    for (int q = 0; q < 4; ++q) {
        if (kq[q] < 0) continue;             // wave-uniform
        H2U u0, u1, u2, u3;
        uint2 p01, p23;
        u0.h = m[q][0]; u1.h = m[q][1]; u2.h = m[q][2]; u3.h = m[q][3];
        p01.x = u0.u; p01.y = u1.u; p23.x = u2.u; p23.y = u3.u;
        *(uint2*)(red + tb + 0) = p01;
        *(uint2*)(red + tb + 2) = p23;
        u0.h = c[q][0]; u1.h = c[q][1]; u2.h = c[q][2]; u3.h = c[q][3];
        p01.x = u0.u; p01.y = u1.u; p23.x = u2.u; p23.y = u3.u;
        *(uint2*)(red + tb + 4) = p01;
        *(uint2*)(red + tb + 6) = p23;

        half2v r2 = ismax ? ninf2 : zz;
        #pragma unroll
        for (int i = 0; i < 8; ++i) {
            H2U t;
            t.u = red[wbase + (sub + 8 * i) * 10 + dv];
            r2 = ismax ? __builtin_elementwise_max(r2, t.h) : (r2 + t.h);
        }
        #pragma unroll
        for (int s = 1; s < 8; s <<= 1) {
            H2U me, ot;
            me.h = r2;
            ot.u = (unsigned int)__shfl_xor((int)me.u, s, 64);
            r2 = ismax ? __builtin_elementwise_max(r2, ot.h) : (r2 + ot.h);
        }
        if (sub == 0) {
            int kk = kq[q];
            if (ismax) {
                int b = 2 * dv;
                out[(size_t)b       * (2 * NK) + 2 * kk] = (float)r2.x;
                out[(size_t)(b + 1) * (2 * NK) + 2 * kk] = (float)r2.y;
            } else {
                int b = 2 * (dv - 4);
                float inv = 1.0f / (float)lkq[q];
                out[(size_t)b       * (2 * NK) + 2 * kk + 1] = (float)r2.x * inv;
                out[(size_t)(b + 1) * (2 * NK) + 2 * kk + 1] = (float)r2.y * inv;
            }
        }
    }
}

extern "C" void kernel_launch(void* const* d_in, const int* in_sizes, int n_in,
                              void* d_out, int out_size, void* d_ws, size_t ws_size,
                              hipStream_t stream) {
    const float* x    = (const float*)d_in[0];
    const float* W    = (const float*)d_in[1];
    const float* bias = (const float*)d_in[2];
    const int*   dil  = (const int*)d_in[4];
    const int*   lo   = (const int*)d_in[5];
    float* out = (float*)d_out;
    int* ord = (int*)d_ws;                   // TOT_SLOT ints = 76 KiB scratch

    bucket_kernel<<<1, 1024, 0, stream>>>(W, dil, lo, ord);
    rocket_kernel<<<GRID_MAIN, 256, 0, stream>>>(x, W, bias, dil, lo, ord, out);
}

// Round 8
// 103.560 us; speedup vs baseline: 1.0749x; 1.0749x over previous
//
#include <hip/hip_runtime.h>
#include <math.h>

#define NK        10000
#define LSEQ      512
#define KSMAX     11
#define NKEY      3072              // key = (((dl-1)*3 + ksi) << 1) | padded
#define TOT_SLOT  10400             // >= NK + one pad slot per distinct key (~400 max)
#define GRID_MAIN 1300              // 8 slots (4 waves x 1 pair) per block
#define ROWS_DW   (514 * 4)         // staged f16x8 rows (pos=-1..512), dwords
#define RED_OFF   ROWS_DW
#define SM_DW     (ROWS_DW + 256 * 10)   // 18464 B

typedef _Float16 half2v __attribute__((ext_vector_type(2)));
union H2U { half2v h; unsigned int u; };

__device__ __forceinline__ int ks_index(float w7, float w8, float w9, float w10) {
    if (w7 == 0.f && w8 == 0.f && w9 == 0.f && w10 == 0.f) return 0;
    if (w9 == 0.f && w10 == 0.f) return 1;
    return 2;
}

// ---- pass 1: bucket kernels by (dl,ks,pad) into pair-aligned slot regions (no scan) ----
__global__ __launch_bounds__(1024) void bucket_kernel(
    const float* __restrict__ W, const int* __restrict__ dil, const int* __restrict__ lo,
    int* __restrict__ ord) {
    __shared__ unsigned cnt[NKEY];
    __shared__ unsigned cur[NKEY];
    __shared__ unsigned tot;
    const int tid = threadIdx.x;
    if (tid == 0) tot = 0;
    for (int i = tid; i < NKEY; i += 1024) cnt[i] = 0;
    for (int i = tid; i < TOT_SLOT; i += 1024) ord[i] = -1;
    __syncthreads();
    for (int i = tid; i < NK; i += 1024) {
        const float* wr = W + (size_t)i * KSMAX;
        int ksi = ks_index(wr[7], wr[8], wr[9], wr[10]);
        int d = dil[i];
        int pd = (lo[i] - LSEQ + d * (6 + 2 * ksi)) > 0;
        atomicAdd(&cnt[(((d - 1) * 3 + ksi) << 1) | pd], 1u);
    }
    __syncthreads();
    for (int i = tid; i < NKEY; i += 1024) {
        unsigned c = cnt[i];
        if (c) cur[i] = atomicAdd(&tot, (c + 1u) & ~1u);   // pair-aligned region base
    }
    __syncthreads();
    for (int i = tid; i < NK; i += 1024) {
        const float* wr = W + (size_t)i * KSMAX;
        int ksi = ks_index(wr[7], wr[8], wr[9], wr[10]);
        int d = dil[i];
        int pd = (lo[i] - LSEQ + d * (6 + 2 * ksi)) > 0;
        unsigned s = atomicAdd(&cur[(((d - 1) * 3 + ksi) << 1) | pd], 1u);
        ord[s] = i;
    }
}

// ---- main kernel: one wave owns a PAIR of same-(dl,ks,pad) kernels ----
template <int KS>
__device__ __forceinline__ void run_pair(const float4* __restrict__ rows,
                                         const half2v (&wh)[2][KSMAX], const half2v (&bb)[2],
                                         const int (&pq)[2], const int (&lkq)[2],
                                         int dl, int r_lo, int r_hi, int lane,
                                         half2v (&m)[2][4], half2v (&c)[2][4]) {
    const half2v one2  = {(_Float16)1.0f, (_Float16)1.0f};
    const half2v zero2 = {(_Float16)0.0f, (_Float16)0.0f};
    const half2v big2  = {(_Float16)16384.0f, (_Float16)16384.0f};
    const half2v ninf2 = {(_Float16)(-INFINITY), (_Float16)(-INFINITY)};
    for (int r0 = r_lo; r0 < r_hi; r0 += 64) {
        const int r = r0 + lane;
        half2v a[2][4];
        #pragma unroll
        for (int q = 0; q < 2; ++q) {
            #pragma unroll
            for (int i = 0; i < 4; ++i) a[q][i] = bb[q];
        }
        int pos = r;
        #pragma unroll
        for (int j = 0; j < KS; ++j) {
            int pc = min(max(pos, -1), LSEQ);          // v_med3_i32; rows -1/512 are zeros
            float4 rr = rows[pc + 1];                  // ONE ds_read_b128 serves 2 kernels
            half2v v0 = ((half2v*)&rr)[0];
            half2v v1 = ((half2v*)&rr)[1];
            half2v v2 = ((half2v*)&rr)[2];
            half2v v3 = ((half2v*)&rr)[3];
            #pragma unroll
            for (int q = 0; q < 2; ++q) {
                half2v wj = wh[q][j];
                a[q][0] += wj * v0;
                a[q][1] += wj * v1;
                a[q][2] += wj * v2;
                a[q][3] += wj * v3;
            }
            pos += dl;
        }
        #pragma unroll
        for (int q = 0; q < 2; ++q) {
            unsigned t = (unsigned)(r + pq[q]);        // t for this kernel
            bool valid = t < (unsigned)lkq[q];
            #pragma unroll
            for (int i = 0; i < 4; ++i) {
                half2v av = valid ? a[q][i] : ninf2;   // -inf: neutral for max, step()->0
                m[q][i] = __builtin_elementwise_max(m[q][i], av);
                c[q][i] += __builtin_elementwise_min(
                               __builtin_elementwise_max(av * big2, zero2), one2);
            }
        }
    }
}

__global__ __launch_bounds__(256) void rocket_kernel(
    const float* __restrict__ x, const float* __restrict__ W,
    const float* __restrict__ bias, const int* __restrict__ dil,
    const int* __restrict__ lo, const int* __restrict__ ord,
    float* __restrict__ out) {
    __shared__ __align__(16) float sm[SM_DW];
    const int tid = threadIdx.x;
    if (ord[blockIdx.x * 8] < 0) return;      // even slots are dense -> whole block dummy

    // ---- stage x -> LDS as f16, batch-major 16B rows; one row per thread ----
    #pragma unroll
    for (int i = 0; i < 2; ++i) {
        int p = tid + i * 256;
        half2v h0 = {(_Float16)x[0 * LSEQ + p], (_Float16)x[1 * LSEQ + p]};
        half2v h1 = {(_Float16)x[2 * LSEQ + p], (_Float16)x[3 * LSEQ + p]};
        half2v h2 = {(_Float16)x[4 * LSEQ + p], (_Float16)x[5 * LSEQ + p]};
        half2v h3 = {(_Float16)x[6 * LSEQ + p], (_Float16)x[7 * LSEQ + p]};
        float4 v;
        ((half2v*)&v)[0] = h0;
        ((half2v*)&v)[1] = h1;
        ((half2v*)&v)[2] = h2;
        ((half2v*)&v)[3] = h3;
        *(float4*)(sm + (size_t)(p + 1) * 4) = v;
    }
    if (tid < 4)           sm[tid] = 0.0f;                   // row pos=-1
    else if (tid < 8)      sm[513 * 4 + (tid - 4)] = 0.0f;   // row pos=512

    const int wave = tid >> 6;
    const int lane = tid & 63;

    // ---- pair setup (wave-uniform, scalarized via readfirstlane) ----
    int kq[2];
    #pragma unroll
    for (int q = 0; q < 2; ++q)
        kq[q] = __builtin_amdgcn_readfirstlane(ord[blockIdx.x * 8 + wave * 2 + q]);

    half2v wh[2][KSMAX];
    half2v bb[2];
    int pq[2], lkq[2];
    float w7 = 0.f, w8 = 0.f, w9 = 0.f, w10 = 0.f;
    int dl = 1;
    #pragma unroll
    for (int q = 0; q < 2; ++q) {
        int k = kq[q];
        if (k >= 0) {
            const float* wr = W + (size_t)k * KSMAX;
            #pragma unroll
            for (int j = 0; j < KSMAX; ++j) {
                _Float16 wf = (_Float16)wr[j];
                wh[q][j] = (half2v){wf, wf};
            }
            _Float16 bf = (_Float16)bias[k];
            bb[q] = (half2v){bf, bf};
            lkq[q] = lo[k];
            if (q == 0) { w7 = wr[7]; w8 = wr[8]; w9 = wr[9]; w10 = wr[10]; dl = dil[k]; }
        } else {
            #pragma unroll
            for (int j = 0; j < KSMAX; ++j) wh[q][j] = (half2v){(_Float16)0.f, (_Float16)0.f};
            bb[q] = (half2v){(_Float16)0.f, (_Float16)0.f};
            lkq[q] = 0;
        }
    }
    const int ksi = ks_index(w7, w8, w9, w10);   // pair-uniform (key includes ks)
    const int ks = 7 + 2 * ksi;
    int r_lo = 0, r_hi = 0;
    #pragma unroll
    for (int q = 0; q < 2; ++q) {
        if (kq[q] >= 0) {
            pq[q] = (lkq[q] - LSEQ + dl * (ks - 1)) >> 1;   // lo = 512+2p-dl(ks-1)
            r_lo = min(r_lo, -pq[q]);
            r_hi = max(r_hi, lkq[q] - pq[q]);
        } else {
            pq[q] = 0;
        }
    }

    __syncthreads();   // rows visible to all waves (dummy waves also arrive here)

    const half2v ninf2 = {(_Float16)(-INFINITY), (_Float16)(-INFINITY)};
    const half2v zz    = {(_Float16)0.f, (_Float16)0.f};
    half2v m[2][4], c[2][4];
    #pragma unroll
    for (int q = 0; q < 2; ++q) {
        #pragma unroll
        for (int i = 0; i < 4; ++i) { m[q][i] = ninf2; c[q][i] = zz; }
    }

    const float4* rows = (const float4*)sm;
    if (ksi == 0)      run_pair<7 >(rows, wh, bb, pq, lkq, dl, r_lo, r_hi, lane, m, c);
    else if (ksi == 1) run_pair<9 >(rows, wh, bb, pq, lkq, dl, r_lo, r_hi, lane, m, c);
    else               run_pair<11>(rows, wh, bb, pq, lkq, dl, r_lo, r_hi, lane, m, c);

    // ---- wave-internal epilogue per pair entry (no barriers: same-wave DS ordering) ----
    unsigned int* red = (unsigned int*)(sm + RED_OFF);
    const int tb = tid * 10;                 // 40B stride, 8B aligned
    const int wbase = (tid & ~63) * 10;      // own wave's slice
    const int sub = lane & 7;
    const int dv = lane >> 3;                // 0..3 = max half2s, 4..7 = cnt half2s
    const bool ismax = dv < 4;
    #pragma unroll
    for (int q = 0; q < 2; ++q) {
        if (kq[q] < 0) continue;             // wave-uniform
        H2U u0, u1, u2, u3;
        uint2 p01, p23;
        u0.h = m[q][0]; u1.h = m[q][1]; u2.h = m[q][2]; u3.h = m[q][3];
        p01.x = u0.u; p01.y = u1.u; p23.x = u2.u; p23.y = u3.u;
        *(uint2*)(red + tb + 0) = p01;
        *(uint2*)(red + tb + 2) = p23;
        u0.h = c[q][0]; u1.h = c[q][1]; u2.h = c[q][2]; u3.h = c[q][3];
        p01.x = u0.u; p01.y = u1.u; p23.x = u2.u; p23.y = u3.u;
        *(uint2*)(red + tb + 4) = p01;
        *(uint2*)(red + tb + 6) = p23;

        half2v r2 = ismax ? ninf2 : zz;
        #pragma unroll
        for (int i = 0; i < 8; ++i) {
            H2U t;
            t.u = red[wbase + (sub + 8 * i) * 10 + dv];
            r2 = ismax ? __builtin_elementwise_max(r2, t.h) : (r2 + t.h);
        }
        #pragma unroll
        for (int s = 1; s < 8; s <<= 1) {
            H2U me, ot;
            me.h = r2;
            ot.u = (unsigned int)__shfl_xor((int)me.u, s, 64);
            r2 = ismax ? __builtin_elementwise_max(r2, ot.h) : (r2 + ot.h);
        }
        if (sub == 0) {
            int kk = kq[q];
            if (ismax) {
                int b = 2 * dv;
                out[(size_t)b       * (2 * NK) + 2 * kk] = (float)r2.x;
                out[(size_t)(b + 1) * (2 * NK) + 2 * kk] = (float)r2.y;
            } else {
                int b = 2 * (dv - 4);
                float inv = 1.0f / (float)lkq[q];
                out[(size_t)b       * (2 * NK) + 2 * kk + 1] = (float)r2.x * inv;
                out[(size_t)(b + 1) * (2 * NK) + 2 * kk + 1] = (float)r2.y * inv;
            }
        }
    }
}

extern "C" void kernel_launch(void* const* d_in, const int* in_sizes, int n_in,
                              void* d_out, int out_size, void* d_ws, size_t ws_size,
                              hipStream_t stream) {
    const float* x    = (const float*)d_in[0];
    const float* W    = (const float*)d_in[1];
    const float* bias = (const float*)d_in[2];
    const int*   dil  = (const int*)d_in[4];
    const int*   lo   = (const int*)d_in[5];
    float* out = (float*)d_out;
    int* ord = (int*)d_ws;                   // TOT_SLOT ints = 41.6 KiB scratch

    bucket_kernel<<<1, 1024, 0, stream>>>(W, dil, lo, ord);
    rocket_kernel<<<GRID_MAIN, 256, 0, stream>>>(x, W, bias, dil, lo, ord, out);
}

// Round 9
// 86.190 us; speedup vs baseline: 1.2916x; 1.2015x over previous
//
#include <hip/hip_runtime.h>
#include <math.h>

#define NK       10000
#define LSEQ     512
#define KSMAX    11
#define POOLS    32
#define CNT_STRIDE 64                 // ints; 256B between counters -> no same-line atomics
#define GRID_MAIN 2048                // 8 blocks/CU persistent
#define ROWS_DW  (514 * 4)            // staged f16x8 rows (pos=-1..512), dwords
#define RED_OFF  ROWS_DW
#define SM_DW    (ROWS_DW + 256 * 10) // 18464 B -> 8 blocks/CU

typedef _Float16 half2v __attribute__((ext_vector_type(2)));
union H2U { half2v h; unsigned int u; };

template <int KS>
__device__ __forceinline__ void run_conv(const float4* __restrict__ rows,
                                         const half2v* __restrict__ wh, half2v bb,
                                         int pad, int dl, int lk, int lane,
                                         half2v& m0, half2v& m1, half2v& m2, half2v& m3,
                                         half2v& c0, half2v& c1, half2v& c2, half2v& c3) {
    const half2v one2  = {(_Float16)1.0f, (_Float16)1.0f};
    const half2v zero2 = {(_Float16)0.0f, (_Float16)0.0f};
    const half2v big2  = {(_Float16)16384.0f, (_Float16)16384.0f};
    for (int t0 = 0; t0 < lk; t0 += 64) {       // this wave owns the whole k
        const int t = t0 + lane;
        half2v a0 = bb, a1 = bb, a2 = bb, a3 = bb;
        int pos = t - pad;
        #pragma unroll
        for (int j = 0; j < KS; ++j) {
            int pc = min(max(pos, -1), LSEQ);   // v_med3_i32; rows -1/512 are zeros
            float4 r = rows[pc + 1];            // one ds_read_b128 per tap
            half2v wj = wh[j];
            a0 += wj * ((half2v*)&r)[0];        // v_pk_fma_f16
            a1 += wj * ((half2v*)&r)[1];
            a2 += wj * ((half2v*)&r)[2];
            a3 += wj * ((half2v*)&r)[3];
            pos += dl;
        }
        if (t < lk) {
            m0 = __builtin_elementwise_max(m0, a0);
            m1 = __builtin_elementwise_max(m1, a1);
            m2 = __builtin_elementwise_max(m2, a2);
            m3 = __builtin_elementwise_max(m3, a3);
            // step(a) = clamp(a*16384, 0, 1): exact 0/1 for all normal f16
            c0 += __builtin_elementwise_min(__builtin_elementwise_max(a0 * big2, zero2), one2);
            c1 += __builtin_elementwise_min(__builtin_elementwise_max(a1 * big2, zero2), one2);
            c2 += __builtin_elementwise_min(__builtin_elementwise_max(a2 * big2, zero2), one2);
            c3 += __builtin_elementwise_min(__builtin_elementwise_max(a3 * big2, zero2), one2);
        }
    }
}

__global__ __launch_bounds__(256) void rocket_kernel(
    const float* __restrict__ x, const float* __restrict__ W,
    const float* __restrict__ bias, const int* __restrict__ dil,
    const int* __restrict__ lo, int* __restrict__ cnt,
    float* __restrict__ out) {
    __shared__ __align__(16) float sm[SM_DW];
    const int tid  = threadIdx.x;
    const int wave = tid >> 6;
    const int lane = tid & 63;
    (void)wave;

    // ---- stage x -> LDS as f16, batch-major 16B rows; one row per thread ----
    #pragma unroll
    for (int i = 0; i < 2; ++i) {
        int p = tid + i * 256;
        half2v h0 = {(_Float16)x[0 * LSEQ + p], (_Float16)x[1 * LSEQ + p]};
        half2v h1 = {(_Float16)x[2 * LSEQ + p], (_Float16)x[3 * LSEQ + p]};
        half2v h2 = {(_Float16)x[4 * LSEQ + p], (_Float16)x[5 * LSEQ + p]};
        half2v h3 = {(_Float16)x[6 * LSEQ + p], (_Float16)x[7 * LSEQ + p]};
        float4 v;
        ((half2v*)&v)[0] = h0;
        ((half2v*)&v)[1] = h1;
        ((half2v*)&v)[2] = h2;
        ((half2v*)&v)[3] = h3;
        *(float4*)(sm + (size_t)(p + 1) * 4) = v;      // contiguous 16B rows
    }
    if (tid < 4)           sm[tid] = 0.0f;                   // row pos=-1
    else if (tid < 8)      sm[513 * 4 + (tid - 4)] = 0.0f;   // row pos=512

    __syncthreads();   // the only block barrier: rows visible to all waves

    const int pool = blockIdx.x & (POOLS - 1);
    const int poolsize = (NK - pool + POOLS - 1) / POOLS;    // #k in this pool
    int* pc = cnt + pool * CNT_STRIDE;

    const float4* rows = (const float4*)sm;
    unsigned int* red = (unsigned int*)(sm + RED_OFF);
    const int tb = tid * 10;                 // 40B stride, 8B aligned
    const int wbase = (tid & ~63) * 10;      // own wave's slice
    const int sub = lane & 7;
    const int dv = lane >> 3;                // 0..3 = max half2s, 4..7 = cnt half2s
    const bool ismax = dv < 4;
    const half2v ninf2 = {(_Float16)(-INFINITY), (_Float16)(-INFINITY)};
    const half2v zz    = {(_Float16)0.f, (_Float16)0.f};

    while (true) {
        // ---- dynamic grab: one k per wave per round ----
        int n = 0;
        if (lane == 0) n = atomicAdd(pc, 1);
        n = __shfl(n, 0, 64);
        if (n >= poolsize) break;
        const int k = __builtin_amdgcn_readfirstlane(pool + POOLS * n);

        // ---- per-k params (wave-uniform) ----
        const float* wr = W + (size_t)k * KSMAX;
        half2v wh[KSMAX];
        #pragma unroll
        for (int j = 0; j < KSMAX; ++j) {
            _Float16 wf = (_Float16)wr[j];
            wh[j] = (half2v){wf, wf};
        }
        const float w7 = wr[7], w8 = wr[8], w9 = wr[9], w10 = wr[10];
        _Float16 bf = (_Float16)bias[k];
        const half2v bb = {bf, bf};
        const int dl = dil[k];
        const int lk = lo[k];

        half2v m0 = ninf2, m1 = ninf2, m2 = ninf2, m3 = ninf2;
        half2v c0 = zz,    c1 = zz,    c2 = zz,    c3 = zz;

        // ks from trailing zero weights; pad from lo = 512 + 2*pad - dl*(ks-1)
        const bool z7 = (w7 == 0.f) && (w8 == 0.f) && (w9 == 0.f) && (w10 == 0.f);
        const bool z9 = (w9 == 0.f) && (w10 == 0.f);
        if (z7) {
            int pad = (lk - LSEQ + dl * 6) >> 1;
            run_conv<7 >(rows, wh, bb, pad, dl, lk, lane, m0, m1, m2, m3, c0, c1, c2, c3);
        } else if (z9) {
            int pad = (lk - LSEQ + dl * 8) >> 1;
            run_conv<9 >(rows, wh, bb, pad, dl, lk, lane, m0, m1, m2, m3, c0, c1, c2, c3);
        } else {
            int pad = (lk - LSEQ + dl * 10) >> 1;
            run_conv<11>(rows, wh, bb, pad, dl, lk, lane, m0, m1, m2, m3, c0, c1, c2, c3);
        }

        // ---- wave-internal epilogue (no barriers: same-wave DS ordering) ----
        H2U u0, u1, u2, u3;
        uint2 p01, p23;
        u0.h = m0; u1.h = m1; u2.h = m2; u3.h = m3;
        p01.x = u0.u; p01.y = u1.u; p23.x = u2.u; p23.y = u3.u;
        *(uint2*)(red + tb + 0) = p01;
        *(uint2*)(red + tb + 2) = p23;
        u0.h = c0; u1.h = c1; u2.h = c2; u3.h = c3;
        p01.x = u0.u; p01.y = u1.u; p23.x = u2.u; p23.y = u3.u;
        *(uint2*)(red + tb + 4) = p01;
        *(uint2*)(red + tb + 6) = p23;

        half2v r2 = ismax ? ninf2 : zz;
        #pragma unroll
        for (int i = 0; i < 8; ++i) {
            H2U t;
            t.u = red[wbase + (sub + 8 * i) * 10 + dv];
            r2 = ismax ? __builtin_elementwise_max(r2, t.h) : (r2 + t.h);
        }
        #pragma unroll
        for (int s = 1; s < 8; s <<= 1) {
            H2U me, ot;
            me.h = r2;
            ot.u = (unsigned int)__shfl_xor((int)me.u, s, 64);
            r2 = ismax ? __builtin_elementwise_max(r2, ot.h) : (r2 + ot.h);
        }
        if (sub == 0) {
            if (ismax) {
                int b = 2 * dv;
                out[(size_t)b       * (2 * NK) + 2 * k] = (float)r2.x;
                out[(size_t)(b + 1) * (2 * NK) + 2 * k] = (float)r2.y;
            } else {
                int b = 2 * (dv - 4);
                float inv = 1.0f / (float)lk;
                out[(size_t)b       * (2 * NK) + 2 * k + 1] = (float)r2.x * inv;
                out[(size_t)(b + 1) * (2 * NK) + 2 * k + 1] = (float)r2.y * inv;
            }
        }
    }
}

extern "C" void kernel_launch(void* const* d_in, const int* in_sizes, int n_in,
                              void* d_out, int out_size, void* d_ws, size_t ws_size,
                              hipStream_t stream) {
    const float* x    = (const float*)d_in[0];
    const float* W    = (const float*)d_in[1];
    const float* bias = (const float*)d_in[2];
    const int*   dil  = (const int*)d_in[4];
    const int*   lo   = (const int*)d_in[5];
    float* out = (float*)d_out;
    int* cnt = (int*)d_ws;                   // POOLS counters, 256B apart

    hipMemsetAsync(cnt, 0, POOLS * CNT_STRIDE * sizeof(int), stream);
    rocket_kernel<<<GRID_MAIN, 256, 0, stream>>>(x, W, bias, dil, lo, cnt, out);
}